// Round 1
// baseline (142.022 us; speedup 1.0000x reference)
//
#include <hip/hip_runtime.h>
#include <math.h>

// Cosine similarity per matching row: out[r] = dot(a[r,:], b[r,:]) /
// (||a[r,:]|| * ||b[r,:]||), D = 256 floats per row, eps-guarded.
//
// Round-5: single-variable change vs round-4 — drop __builtin_nontemporal_load.
// Inputs are 2 x 64 MiB = 128 MB < 256 MB Infinity Cache: the nt flag
// (no-allocate) forcibly defeats L3 residency across bench iterations and is
// the prime suspect for the previously observed ~3 TB/s read ceiling.
// Structure is unchanged and already BW-optimal:
//  - 1 wave per row-quad per iteration: 8 contiguous 1 KiB wave-loads
//    (4 rows x {a,b}) issued back-to-back into NAMED registers (8-deep MLP).
//  - 64 lanes x 16 B = exactly one row (1 KiB) per wave-load, fully coalesced.
//  - 2048 blocks x 4 waves = 8192 waves = the chip's full wave capacity;
//    VGPRs stay under 64 so we keep 8 waves/SIMD.

#define EPS 1e-12f

typedef float f4 __attribute__((ext_vector_type(4)));

__global__ __launch_bounds__(256) void cosine_rows_kernel(
    const f4* __restrict__ a4,
    const f4* __restrict__ b4,
    float* __restrict__ out,
    int nrows)
{
    const int lane = threadIdx.x & 63;
    const int wid  = (blockIdx.x << 2) + (threadIdx.x >> 6);
    const int nw   = gridDim.x << 2;

    for (int base = wid * 4; base < nrows; base += nw * 4) {
        // 8 independent 1 KiB wave-loads, all issued before any use.
        const int i0 = (base + 0) * 64 + lane;
        const int i1 = (base + 1) * 64 + lane;
        const int i2 = (base + 2) * 64 + lane;
        const int i3 = (base + 3) * 64 + lane;
        f4 av0 = a4[i0];
        f4 av1 = a4[i1];
        f4 av2 = a4[i2];
        f4 av3 = a4[i3];
        f4 bv0 = b4[i0];
        f4 bv1 = b4[i1];
        f4 bv2 = b4[i2];
        f4 bv3 = b4[i3];

        f4 avs[4] = {av0, av1, av2, av3};
        f4 bvs[4] = {bv0, bv1, bv2, bv3};

        #pragma unroll
        for (int r = 0; r < 4; ++r) {
            const f4 av = avs[r];
            const f4 bv = bvs[r];
            float saa = av.x * av.x + av.y * av.y + av.z * av.z + av.w * av.w;
            float sbb = bv.x * bv.x + bv.y * bv.y + bv.z * bv.z + bv.w * bv.w;
            float sab = av.x * bv.x + av.y * bv.y + av.z * bv.z + av.w * bv.w;

            #pragma unroll
            for (int off = 32; off > 0; off >>= 1) {
                saa += __shfl_xor(saa, off, 64);
                sbb += __shfl_xor(sbb, off, 64);
                sab += __shfl_xor(sab, off, 64);
            }

            if (lane == 0) {
                const float denom = sqrtf(fmaxf(saa, EPS)) * sqrtf(fmaxf(sbb, EPS));
                out[base + r] = sab / denom;
            }
        }
    }
}

extern "C" void kernel_launch(void* const* d_in, const int* in_sizes, int n_in,
                              void* d_out, int out_size, void* d_ws, size_t ws_size,
                              hipStream_t stream) {
    const float* a = (const float*)d_in[0];
    const float* b = (const float*)d_in[1];
    float* out = (float*)d_out;

    const int nrows = out_size;   // 16 * 4096 = 65536 (divisible by 4)
    const int blocks = 2048;      // 8 blocks/CU target; 2 sweeps per wave

    cosine_rows_kernel<<<blocks, 256, 0, stream>>>(
        (const f4*)a, (const f4*)b, out, nrows);
}